// Round 1
// baseline (1839.407 us; speedup 1.0000x reference)
//
#include <hip/hip_runtime.h>

#define NN 50000
#define NE 600000
#define D 128
#define NREL 2

// ---------------- edge type + per-relation in-degree ----------------
__global__ void k_etype_count(const float* __restrict__ attr,
                              const int* __restrict__ dst,
                              int* __restrict__ etype,
                              int* __restrict__ cnt, int E) {
    int i = blockIdx.x * blockDim.x + threadIdx.x;
    if (i >= E) return;
    float2 a = reinterpret_cast<const float2*>(attr)[i];
    int r = (a.y > a.x) ? 1 : 0;   // argmax, first-index tiebreak
    etype[i] = r;
    atomicAdd(&cnt[r * NN + dst[i]], 1);
}

__global__ void k_inv(const int* __restrict__ cnt, float* __restrict__ inv) {
    int i = blockIdx.x * blockDim.x + threadIdx.x;
    if (i >= NREL * NN) return;
    int c = cnt[i];
    inv[i] = 1.0f / (float)(c > 1 ? c : 1);
}

// ---------------- scatter: one wave per edge, atomic accumulate ----------------
__global__ void k_scatter(const float* __restrict__ h,
                          const int* __restrict__ src,
                          const int* __restrict__ dst,
                          const int* __restrict__ etype,
                          float* __restrict__ agg, int E) {
    int gtid = blockIdx.x * blockDim.x + threadIdx.x;
    int wid = gtid >> 6;
    int lane = threadIdx.x & 63;
    if (wid >= E) return;
    int s = src[wid], d = dst[wid], r = etype[wid];
    float2 v = *reinterpret_cast<const float2*>(h + (size_t)s * D + lane * 2);
    float* p = agg + ((size_t)r * NN + d) * D + lane * 2;
    atomicAdd(p + 0, v.x);
    atomicAdd(p + 1, v.y);
}

// ---------------- fused GEMM: out = relu([A0|A1*inv1|A2*inv2] @ [W0;W1;W2] + bias) ----
// BM=64, BN=128(full), BK=32, 256 threads, 8x4 micro-tile per thread.
template <int NCHUNK>
__global__ __launch_bounds__(256)
void k_gemm_relu(const float* __restrict__ A0, const float* __restrict__ A1,
                 const float* __restrict__ A2,
                 const float* __restrict__ inv1, const float* __restrict__ inv2,
                 const float* __restrict__ W0, const float* __restrict__ W1,
                 const float* __restrict__ W2,
                 const float* __restrict__ bias,
                 float* __restrict__ out, int N) {
    __shared__ float sA[64][32];
    __shared__ float sB[32][128];
    const int tid = threadIdx.x;
    const int tx = tid & 31;   // col group: cols tx*4 .. tx*4+3
    const int ty = tid >> 5;   // row group: rows ty*8 .. ty*8+7
    const int row0 = blockIdx.x * 64;

    float acc[8][4];
#pragma unroll
    for (int i = 0; i < 8; i++)
#pragma unroll
        for (int j = 0; j < 4; j++) acc[i][j] = 0.f;

    const float* As[3]   = {A0, A1, A2};
    const float* Ws[3]   = {W0, W1, W2};
    const float* invs[3] = {nullptr, inv1, inv2};

#pragma unroll
    for (int c = 0; c < NCHUNK; ++c) {
        const float* A    = As[c];
        const float* Wc   = Ws[c];
        const float* invc = invs[c];
        for (int kb = 0; kb < 4; ++kb) {
            // stage A tile 64x32 (2 x float4 per thread)
            {
                int r  = tid >> 3;            // 0..31
                int cg = (tid & 7) * 4;       // 0..28
#pragma unroll
                for (int h2 = 0; h2 < 2; ++h2) {
                    int rr = r + h2 * 32;
                    int grow = row0 + rr;
                    float4 v = make_float4(0.f, 0.f, 0.f, 0.f);
                    if (grow < N) {
                        v = *reinterpret_cast<const float4*>(
                            A + (size_t)grow * D + kb * 32 + cg);
                        if (invc) {
                            float s = invc[grow];
                            v.x *= s; v.y *= s; v.z *= s; v.w *= s;
                        }
                    }
                    *reinterpret_cast<float4*>(&sA[rr][cg]) = v;
                }
            }
            // stage B tile 32x128 (4 x float4 per thread)
            {
#pragma unroll
                for (int h2 = 0; h2 < 4; ++h2) {
                    int f  = tid + h2 * 256;   // 0..1023
                    int br = f >> 5;
                    int bc = (f & 31) * 4;
                    *reinterpret_cast<float4*>(&sB[br][bc]) =
                        *reinterpret_cast<const float4*>(
                            Wc + (size_t)(kb * 32 + br) * D + bc);
                }
            }
            __syncthreads();
#pragma unroll
            for (int k = 0; k < 32; ++k) {
                float a[8];
#pragma unroll
                for (int i = 0; i < 8; i++) a[i] = sA[ty * 8 + i][k];
                float4 bv = *reinterpret_cast<const float4*>(&sB[k][tx * 4]);
                float b[4] = {bv.x, bv.y, bv.z, bv.w};
#pragma unroll
                for (int i = 0; i < 8; i++)
#pragma unroll
                    for (int j = 0; j < 4; j++)
                        acc[i][j] = fmaf(a[i], b[j], acc[i][j]);
            }
            __syncthreads();
        }
    }
    // epilogue: bias + relu + store
    float4 bv = *reinterpret_cast<const float4*>(bias + tx * 4);
#pragma unroll
    for (int i = 0; i < 8; i++) {
        int grow = row0 + ty * 8 + i;
        if (grow < N) {
            float4 o;
            o.x = acc[i][0] + bv.x;
            o.y = acc[i][1] + bv.y;
            o.z = acc[i][2] + bv.z;
            o.w = acc[i][3] + bv.w;
            o.x = o.x > 0.f ? o.x : 0.f;
            o.y = o.y > 0.f ? o.y : 0.f;
            o.z = o.z > 0.f ? o.z : 0.f;
            o.w = o.w > 0.f ? o.w : 0.f;
            *reinterpret_cast<float4*>(out + (size_t)grow * D + tx * 4) = o;
        }
    }
}

extern "C" void kernel_launch(void* const* d_in, const int* in_sizes, int n_in,
                              void* d_out, int out_size, void* d_ws, size_t ws_size,
                              hipStream_t stream) {
    const float* x    = (const float*)d_in[0];
    const int*   ei   = (const int*)d_in[1];
    const float* attr = (const float*)d_in[2];
    const float* Wf   = (const float*)d_in[3];
    const float* bf   = (const float*)d_in[4];
    const float* cw   = (const float*)d_in[5];  // [3][2][128][128]
    const float* cr   = (const float*)d_in[6];  // [3][128][128]
    const float* cb   = (const float*)d_in[7];  // [3][128]
    const int* src  = ei;
    const int* dstv = ei + NE;

    // workspace layout
    float* h0   = (float*)d_ws;                       // NN*D
    float* h1   = h0 + (size_t)NN * D;                // NN*D
    float* agg  = h1 + (size_t)NN * D;                // 2*NN*D
    float* inv  = agg + (size_t)2 * NN * D;           // 2*NN
    int*   cnt  = (int*)(inv + (size_t)2 * NN);       // 2*NN
    int*   etyp = cnt + (size_t)2 * NN;               // NE

    float* outp = (float*)d_out;

    // edge types + per-relation counts (layer-invariant)
    hipMemsetAsync(cnt, 0, (size_t)2 * NN * sizeof(int), stream);
    k_etype_count<<<(NE + 255) / 256, 256, 0, stream>>>(attr, dstv, etyp, cnt, NE);
    k_inv<<<(2 * NN + 255) / 256, 256, 0, stream>>>(cnt, inv);

    const int gblocks = (NN + 63) / 64;
    // input projection: h0 = relu(x @ Wf + bf)
    k_gemm_relu<1><<<gblocks, 256, 0, stream>>>(
        x, nullptr, nullptr, nullptr, nullptr,
        Wf, nullptr, nullptr, bf, h0, NN);

    const int sblocks = (NE * 64 + 255) / 256;  // one wave per edge
    for (int l = 0; l < 3; ++l) {
        const float* hin = (l == 1) ? h1 : h0;
        float* hout = (l == 0) ? h1 : (l == 1) ? h0 : outp;

        hipMemsetAsync(agg, 0, (size_t)2 * NN * D * sizeof(float), stream);
        k_scatter<<<sblocks, 256, 0, stream>>>(hin, src, dstv, etyp, agg, NE);
        k_gemm_relu<3><<<gblocks, 256, 0, stream>>>(
            hin, agg, agg + (size_t)NN * D,
            inv, inv + NN,
            cr + (size_t)l * D * D,
            cw + (size_t)(l * 2 + 0) * D * D,
            cw + (size_t)(l * 2 + 1) * D * D,
            cb + (size_t)l * D,
            hout, NN);
    }
}

// Round 2
// 680.883 us; speedup vs baseline: 2.7015x; 2.7015x over previous
//
#include <hip/hip_runtime.h>

#define NN 50000
#define NE 600000
#define D 128
#define NREL 2

// ---------------- edge type + per-relation in-degree ----------------
__global__ void k_etype_count(const float* __restrict__ attr,
                              const int* __restrict__ dst,
                              int* __restrict__ etype,
                              int* __restrict__ cnt, int E) {
    int i = blockIdx.x * blockDim.x + threadIdx.x;
    if (i >= E) return;
    float2 a = reinterpret_cast<const float2*>(attr)[i];
    int r = (a.y > a.x) ? 1 : 0;   // argmax, first-index tiebreak
    etype[i] = r;
    atomicAdd(&cnt[r * NN + dst[i]], 1);
}

__global__ void k_inv(const int* __restrict__ cnt, float* __restrict__ inv) {
    int i = blockIdx.x * blockDim.x + threadIdx.x;
    if (i >= NREL * NN) return;
    int c = cnt[i];
    inv[i] = 1.0f / (float)(c > 1 ? c : 1);
}

// ---------------- exclusive scan of cnt[2*NN] -> off[2*NN+1], single block ----
__global__ __launch_bounds__(1024)
void k_scan(const int* __restrict__ cnt, int* __restrict__ off) {
    __shared__ int sums[1024];
    const int M = NREL * NN;            // 100000
    const int T = 1024;
    const int per = (M + T - 1) / T;    // 98
    int t = threadIdx.x;
    int lo = t * per;
    int hi = lo + per; if (hi > M) hi = M;
    int s = 0;
    for (int i = lo; i < hi; i++) s += cnt[i];
    sums[t] = s;
    __syncthreads();
    for (int d = 1; d < T; d <<= 1) {
        int v = (t >= d) ? sums[t - d] : 0;
        __syncthreads();
        sums[t] += v;
        __syncthreads();
    }
    int base = (t == 0) ? 0 : sums[t - 1];
    for (int i = lo; i < hi; i++) { off[i] = base; base += cnt[i]; }
    if (t == T - 1) off[M] = base;
}

// ---------------- fill CSR: srcs[pos] = src[e], bucketed by (rel,dst) --------
__global__ void k_fill(const int* __restrict__ src, const int* __restrict__ dst,
                       const int* __restrict__ etype,
                       int* __restrict__ cursor, int* __restrict__ srcs, int E) {
    int i = blockIdx.x * blockDim.x + threadIdx.x;
    if (i >= E) return;
    int key = etype[i] * NN + dst[i];
    int pos = atomicAdd(&cursor[key], 1);
    srcs[pos] = src[i];
}

// ---------------- aggregation: one wave per (rel,node), atomic-free ----------
__global__ __launch_bounds__(256)
void k_aggregate(const float* __restrict__ h, const int* __restrict__ srcs,
                 const int* __restrict__ off, const float* __restrict__ inv,
                 float* __restrict__ agg) {
    int wid = (blockIdx.x * blockDim.x + threadIdx.x) >> 6;
    int lane = threadIdx.x & 63;
    if (wid >= NREL * NN) return;
    int start = off[wid], end = off[wid + 1];
    float2 acc = make_float2(0.f, 0.f);
    int e = start;
    for (; e + 1 < end; e += 2) {       // 2-deep unroll: two loads in flight
        int s0 = srcs[e], s1 = srcs[e + 1];
        float2 v0 = *reinterpret_cast<const float2*>(h + (size_t)s0 * D + lane * 2);
        float2 v1 = *reinterpret_cast<const float2*>(h + (size_t)s1 * D + lane * 2);
        acc.x += v0.x + v1.x;
        acc.y += v0.y + v1.y;
    }
    if (e < end) {
        int s0 = srcs[e];
        float2 v0 = *reinterpret_cast<const float2*>(h + (size_t)s0 * D + lane * 2);
        acc.x += v0.x; acc.y += v0.y;
    }
    float sc = inv[wid];
    *reinterpret_cast<float2*>(agg + (size_t)wid * D + lane * 2) =
        make_float2(acc.x * sc, acc.y * sc);
}

// ---------------- fused GEMM: out = relu([A0|A1|A2] @ [W0;W1;W2] + bias) ----
// BM=64, BN=128(full), BK=32, 256 threads, 8x4 micro-tile per thread.
template <int NCHUNK>
__global__ __launch_bounds__(256)
void k_gemm_relu(const float* __restrict__ A0, const float* __restrict__ A1,
                 const float* __restrict__ A2,
                 const float* __restrict__ W0, const float* __restrict__ W1,
                 const float* __restrict__ W2,
                 const float* __restrict__ bias,
                 float* __restrict__ out, int N) {
    __shared__ float sA[64][32];
    __shared__ float sB[32][128];
    const int tid = threadIdx.x;
    const int tx = tid & 31;   // col group: cols tx*4 .. tx*4+3
    const int ty = tid >> 5;   // row group: rows ty*8 .. ty*8+7
    const int row0 = blockIdx.x * 64;

    float acc[8][4];
#pragma unroll
    for (int i = 0; i < 8; i++)
#pragma unroll
        for (int j = 0; j < 4; j++) acc[i][j] = 0.f;

    const float* As[3] = {A0, A1, A2};
    const float* Ws[3] = {W0, W1, W2};

#pragma unroll
    for (int c = 0; c < NCHUNK; ++c) {
        const float* A  = As[c];
        const float* Wc = Ws[c];
        for (int kb = 0; kb < 4; ++kb) {
            // stage A tile 64x32 (2 x float4 per thread)
            {
                int r  = tid >> 3;            // 0..31
                int cg = (tid & 7) * 4;       // 0..28
#pragma unroll
                for (int h2 = 0; h2 < 2; ++h2) {
                    int rr = r + h2 * 32;
                    int grow = row0 + rr;
                    float4 v = make_float4(0.f, 0.f, 0.f, 0.f);
                    if (grow < N) {
                        v = *reinterpret_cast<const float4*>(
                            A + (size_t)grow * D + kb * 32 + cg);
                    }
                    *reinterpret_cast<float4*>(&sA[rr][cg]) = v;
                }
            }
            // stage B tile 32x128 (4 x float4 per thread)
            {
#pragma unroll
                for (int h2 = 0; h2 < 4; ++h2) {
                    int f  = tid + h2 * 256;   // 0..1023
                    int br = f >> 5;
                    int bc = (f & 31) * 4;
                    *reinterpret_cast<float4*>(&sB[br][bc]) =
                        *reinterpret_cast<const float4*>(
                            Wc + (size_t)(kb * 32 + br) * D + bc);
                }
            }
            __syncthreads();
#pragma unroll
            for (int k = 0; k < 32; ++k) {
                float a[8];
#pragma unroll
                for (int i = 0; i < 8; i++) a[i] = sA[ty * 8 + i][k];
                float4 bv = *reinterpret_cast<const float4*>(&sB[k][tx * 4]);
                float b[4] = {bv.x, bv.y, bv.z, bv.w};
#pragma unroll
                for (int i = 0; i < 8; i++)
#pragma unroll
                    for (int j = 0; j < 4; j++)
                        acc[i][j] = fmaf(a[i], b[j], acc[i][j]);
            }
            __syncthreads();
        }
    }
    // epilogue: bias + relu + store
    float4 bv = *reinterpret_cast<const float4*>(bias + tx * 4);
#pragma unroll
    for (int i = 0; i < 8; i++) {
        int grow = row0 + ty * 8 + i;
        if (grow < N) {
            float4 o;
            o.x = acc[i][0] + bv.x;
            o.y = acc[i][1] + bv.y;
            o.z = acc[i][2] + bv.z;
            o.w = acc[i][3] + bv.w;
            o.x = o.x > 0.f ? o.x : 0.f;
            o.y = o.y > 0.f ? o.y : 0.f;
            o.z = o.z > 0.f ? o.z : 0.f;
            o.w = o.w > 0.f ? o.w : 0.f;
            *reinterpret_cast<float4*>(out + (size_t)grow * D + tx * 4) = o;
        }
    }
}

extern "C" void kernel_launch(void* const* d_in, const int* in_sizes, int n_in,
                              void* d_out, int out_size, void* d_ws, size_t ws_size,
                              hipStream_t stream) {
    const float* x    = (const float*)d_in[0];
    const int*   ei   = (const int*)d_in[1];
    const float* attr = (const float*)d_in[2];
    const float* Wf   = (const float*)d_in[3];
    const float* bf   = (const float*)d_in[4];
    const float* cw   = (const float*)d_in[5];  // [3][2][128][128]
    const float* cr   = (const float*)d_in[6];  // [3][128][128]
    const float* cb   = (const float*)d_in[7];  // [3][128]
    const int* src  = ei;
    const int* dstv = ei + NE;

    // workspace layout (elements)
    float* h0   = (float*)d_ws;                       // NN*D
    float* h1   = h0 + (size_t)NN * D;                // NN*D
    float* agg  = h1 + (size_t)NN * D;                // 2*NN*D
    float* inv  = agg + (size_t)2 * NN * D;           // 2*NN
    int*   cnt  = (int*)(inv + (size_t)2 * NN);       // 2*NN
    int*   etyp = cnt + (size_t)2 * NN;               // NE
    int*   off  = etyp + (size_t)NE;                  // 2*NN+1
    int*   cur  = off + (size_t)(2 * NN + 1);         // 2*NN
    int*   srcs = cur + (size_t)2 * NN;               // NE

    float* outp = (float*)d_out;

    // ---- layer-invariant preprocessing: etype, counts, CSR ----
    hipMemsetAsync(cnt, 0, (size_t)2 * NN * sizeof(int), stream);
    k_etype_count<<<(NE + 255) / 256, 256, 0, stream>>>(attr, dstv, etyp, cnt, NE);
    k_inv<<<(2 * NN + 255) / 256, 256, 0, stream>>>(cnt, inv);
    k_scan<<<1, 1024, 0, stream>>>(cnt, off);
    hipMemcpyAsync(cur, off, (size_t)2 * NN * sizeof(int),
                   hipMemcpyDeviceToDevice, stream);
    k_fill<<<(NE + 255) / 256, 256, 0, stream>>>(src, dstv, etyp, cur, srcs, NE);

    const int gblocks = (NN + 63) / 64;
    // input projection: h0 = relu(x @ Wf + bf)
    k_gemm_relu<1><<<gblocks, 256, 0, stream>>>(
        x, nullptr, nullptr, Wf, nullptr, nullptr, bf, h0, NN);

    const int ablocks = (2 * NN * 64 + 255) / 256;  // one wave per (rel,node)
    for (int l = 0; l < 3; ++l) {
        const float* hin = (l == 1) ? h1 : h0;
        float* hout = (l == 0) ? h1 : (l == 1) ? h0 : outp;

        k_aggregate<<<ablocks, 256, 0, stream>>>(hin, srcs, off, inv, agg);
        k_gemm_relu<3><<<gblocks, 256, 0, stream>>>(
            hin, agg, agg + (size_t)NN * D,
            cr + (size_t)l * D * D,
            cw + (size_t)(l * 2 + 0) * D * D,
            cw + (size_t)(l * 2 + 1) * D * D,
            cb + (size_t)l * D,
            hout, NN);
    }
}

// Round 3
// 544.513 us; speedup vs baseline: 3.3781x; 1.2504x over previous
//
#include <hip/hip_runtime.h>

#define NN 50000
#define NE 600000
#define D 128
#define NREL 2

// ---------------- edge type + per-relation in-degree ----------------
__global__ void k_etype_count(const float* __restrict__ attr,
                              const int* __restrict__ dst,
                              int* __restrict__ etype,
                              int* __restrict__ cnt, int E) {
    int i = blockIdx.x * blockDim.x + threadIdx.x;
    if (i >= E) return;
    float2 a = reinterpret_cast<const float2*>(attr)[i];
    int r = (a.y > a.x) ? 1 : 0;   // argmax, first-index tiebreak
    etype[i] = r;
    atomicAdd(&cnt[r * NN + dst[i]], 1);
}

__global__ void k_inv(const int* __restrict__ cnt, float* __restrict__ inv) {
    int i = blockIdx.x * blockDim.x + threadIdx.x;
    if (i >= NREL * NN) return;
    int c = cnt[i];
    inv[i] = 1.0f / (float)(c > 1 ? c : 1);
}

// ---------------- bucket allocator: off[i] = fetch_add(total, cnt[i]) --------
// Replaces the serial single-block scan. Bucket ranges are contiguous but in
// arbitrary order — aggregation is order-invariant, so that's fine.
__global__ void k_alloc(const int* __restrict__ cnt, int* __restrict__ off,
                        int* __restrict__ total) {
    int i = blockIdx.x * blockDim.x + threadIdx.x;
    if (i >= NREL * NN) return;
    off[i] = atomicAdd(total, cnt[i]);   // wave-coalesced by atomic optimizer
}

// ---------------- fill CSR: srcs[pos] = src[e], bucketed by (rel,dst) --------
__global__ void k_fill(const int* __restrict__ src, const int* __restrict__ dst,
                       const int* __restrict__ etype,
                       int* __restrict__ cursor, int* __restrict__ srcs, int E) {
    int i = blockIdx.x * blockDim.x + threadIdx.x;
    if (i >= E) return;
    int key = etype[i] * NN + dst[i];
    int pos = atomicAdd(&cursor[key], 1);
    srcs[pos] = src[i];
}

// ---------------- aggregation: one wave per (rel,node), atomic-free ----------
__global__ __launch_bounds__(256)
void k_aggregate(const float* __restrict__ h, const int* __restrict__ srcs,
                 const int* __restrict__ off, const int* __restrict__ cnt,
                 const float* __restrict__ inv,
                 float* __restrict__ agg) {
    int wid = (blockIdx.x * blockDim.x + threadIdx.x) >> 6;
    int lane = threadIdx.x & 63;
    if (wid >= NREL * NN) return;
    int start = off[wid], end = start + cnt[wid];
    float2 acc = make_float2(0.f, 0.f);
    int e = start;
    for (; e + 1 < end; e += 2) {       // 2-deep unroll: two loads in flight
        int s0 = srcs[e], s1 = srcs[e + 1];
        float2 v0 = *reinterpret_cast<const float2*>(h + (size_t)s0 * D + lane * 2);
        float2 v1 = *reinterpret_cast<const float2*>(h + (size_t)s1 * D + lane * 2);
        acc.x += v0.x + v1.x;
        acc.y += v0.y + v1.y;
    }
    if (e < end) {
        int s0 = srcs[e];
        float2 v0 = *reinterpret_cast<const float2*>(h + (size_t)s0 * D + lane * 2);
        acc.x += v0.x; acc.y += v0.y;
    }
    float sc = inv[wid];
    *reinterpret_cast<float2*>(agg + (size_t)wid * D + lane * 2) =
        make_float2(acc.x * sc, acc.y * sc);
}

// ---------------- fused GEMM: out = relu([A0|A1|A2] @ [W0;W1;W2] + bias) ----
// BM=64, BN=128(full), BK=32, 256 threads, 8x4 micro-tile per thread.
template <int NCHUNK>
__global__ __launch_bounds__(256)
void k_gemm_relu(const float* __restrict__ A0, const float* __restrict__ A1,
                 const float* __restrict__ A2,
                 const float* __restrict__ W0, const float* __restrict__ W1,
                 const float* __restrict__ W2,
                 const float* __restrict__ bias,
                 float* __restrict__ out, int N) {
    __shared__ float sA[64][32];
    __shared__ float sB[32][128];
    const int tid = threadIdx.x;
    const int tx = tid & 31;   // col group: cols tx*4 .. tx*4+3
    const int ty = tid >> 5;   // row group: rows ty*8 .. ty*8+7
    const int row0 = blockIdx.x * 64;

    float acc[8][4];
#pragma unroll
    for (int i = 0; i < 8; i++)
#pragma unroll
        for (int j = 0; j < 4; j++) acc[i][j] = 0.f;

    const float* As[3] = {A0, A1, A2};
    const float* Ws[3] = {W0, W1, W2};

#pragma unroll
    for (int c = 0; c < NCHUNK; ++c) {
        const float* A  = As[c];
        const float* Wc = Ws[c];
        for (int kb = 0; kb < 4; ++kb) {
            // stage A tile 64x32 (2 x float4 per thread)
            {
                int r  = tid >> 3;            // 0..31
                int cg = (tid & 7) * 4;       // 0..28
#pragma unroll
                for (int h2 = 0; h2 < 2; ++h2) {
                    int rr = r + h2 * 32;
                    int grow = row0 + rr;
                    float4 v = make_float4(0.f, 0.f, 0.f, 0.f);
                    if (grow < N) {
                        v = *reinterpret_cast<const float4*>(
                            A + (size_t)grow * D + kb * 32 + cg);
                    }
                    *reinterpret_cast<float4*>(&sA[rr][cg]) = v;
                }
            }
            // stage B tile 32x128 (4 x float4 per thread)
            {
#pragma unroll
                for (int h2 = 0; h2 < 4; ++h2) {
                    int f  = tid + h2 * 256;   // 0..1023
                    int br = f >> 5;
                    int bc = (f & 31) * 4;
                    *reinterpret_cast<float4*>(&sB[br][bc]) =
                        *reinterpret_cast<const float4*>(
                            Wc + (size_t)(kb * 32 + br) * D + bc);
                }
            }
            __syncthreads();
#pragma unroll
            for (int k = 0; k < 32; ++k) {
                float a[8];
#pragma unroll
                for (int i = 0; i < 8; i++) a[i] = sA[ty * 8 + i][k];
                float4 bv = *reinterpret_cast<const float4*>(&sB[k][tx * 4]);
                float b[4] = {bv.x, bv.y, bv.z, bv.w};
#pragma unroll
                for (int i = 0; i < 8; i++)
#pragma unroll
                    for (int j = 0; j < 4; j++)
                        acc[i][j] = fmaf(a[i], b[j], acc[i][j]);
            }
            __syncthreads();
        }
    }
    // epilogue: bias + relu + store
    float4 bv = *reinterpret_cast<const float4*>(bias + tx * 4);
#pragma unroll
    for (int i = 0; i < 8; i++) {
        int grow = row0 + ty * 8 + i;
        if (grow < N) {
            float4 o;
            o.x = acc[i][0] + bv.x;
            o.y = acc[i][1] + bv.y;
            o.z = acc[i][2] + bv.z;
            o.w = acc[i][3] + bv.w;
            o.x = o.x > 0.f ? o.x : 0.f;
            o.y = o.y > 0.f ? o.y : 0.f;
            o.z = o.z > 0.f ? o.z : 0.f;
            o.w = o.w > 0.f ? o.w : 0.f;
            *reinterpret_cast<float4*>(out + (size_t)grow * D + tx * 4) = o;
        }
    }
}

extern "C" void kernel_launch(void* const* d_in, const int* in_sizes, int n_in,
                              void* d_out, int out_size, void* d_ws, size_t ws_size,
                              hipStream_t stream) {
    const float* x    = (const float*)d_in[0];
    const int*   ei   = (const int*)d_in[1];
    const float* attr = (const float*)d_in[2];
    const float* Wf   = (const float*)d_in[3];
    const float* bf   = (const float*)d_in[4];
    const float* cw   = (const float*)d_in[5];  // [3][2][128][128]
    const float* cr   = (const float*)d_in[6];  // [3][128][128]
    const float* cb   = (const float*)d_in[7];  // [3][128]
    const int* src  = ei;
    const int* dstv = ei + NE;

    // workspace layout (elements)
    float* h0   = (float*)d_ws;                       // NN*D
    float* h1   = h0 + (size_t)NN * D;                // NN*D
    float* agg  = h1 + (size_t)NN * D;                // 2*NN*D
    float* inv  = agg + (size_t)2 * NN * D;           // 2*NN
    int*   cnt  = (int*)(inv + (size_t)2 * NN);       // 2*NN
    int*   etyp = cnt + (size_t)2 * NN;               // NE
    int*   off  = etyp + (size_t)NE;                  // 2*NN
    int*   cur  = off + (size_t)2 * NN;               // 2*NN
    int*   srcs = cur + (size_t)2 * NN;               // NE
    int*   total= srcs + (size_t)NE;                  // 1

    float* outp = (float*)d_out;

    // ---- layer-invariant preprocessing: etype, counts, CSR buckets ----
    hipMemsetAsync(cnt, 0, (size_t)2 * NN * sizeof(int), stream);
    hipMemsetAsync(total, 0, sizeof(int), stream);
    k_etype_count<<<(NE + 255) / 256, 256, 0, stream>>>(attr, dstv, etyp, cnt, NE);
    k_inv<<<(2 * NN + 255) / 256, 256, 0, stream>>>(cnt, inv);
    k_alloc<<<(2 * NN + 255) / 256, 256, 0, stream>>>(cnt, off, total);
    hipMemcpyAsync(cur, off, (size_t)2 * NN * sizeof(int),
                   hipMemcpyDeviceToDevice, stream);
    k_fill<<<(NE + 255) / 256, 256, 0, stream>>>(src, dstv, etyp, cur, srcs, NE);

    const int gblocks = (NN + 63) / 64;
    // input projection: h0 = relu(x @ Wf + bf)
    k_gemm_relu<1><<<gblocks, 256, 0, stream>>>(
        x, nullptr, nullptr, Wf, nullptr, nullptr, bf, h0, NN);

    const int ablocks = (2 * NN * 64 + 255) / 256;  // one wave per (rel,node)
    for (int l = 0; l < 3; ++l) {
        const float* hin = (l == 1) ? h1 : h0;
        float* hout = (l == 0) ? h1 : (l == 1) ? h0 : outp;

        k_aggregate<<<ablocks, 256, 0, stream>>>(hin, srcs, off, cnt, inv, agg);
        k_gemm_relu<3><<<gblocks, 256, 0, stream>>>(
            hin, agg, agg + (size_t)NN * D,
            cr + (size_t)l * D * D,
            cw + (size_t)(l * 2 + 0) * D * D,
            cw + (size_t)(l * 2 + 1) * D * D,
            cb + (size_t)l * D,
            hout, NN);
    }
}

// Round 4
// 319.316 us; speedup vs baseline: 5.7605x; 1.7052x over previous
//
#include <hip/hip_runtime.h>
#include <hip/hip_bf16.h>

#define NN 50000
#define NE 600000
#define D 128
#define NREL 2
#define BM 128

typedef __attribute__((ext_vector_type(8))) short bf16x8;   // 8 bf16 (4 VGPRs)
typedef __attribute__((ext_vector_type(4))) float f32x4;    // 4 fp32 acc

// ---------------- edge type + per-relation in-degree ----------------
__global__ void k_etype_count(const float* __restrict__ attr,
                              const int* __restrict__ dst,
                              int* __restrict__ etype,
                              int* __restrict__ cnt, int E) {
    int i = blockIdx.x * blockDim.x + threadIdx.x;
    if (i >= E) return;
    float2 a = reinterpret_cast<const float2*>(attr)[i];
    int r = (a.y > a.x) ? 1 : 0;   // argmax, first-index tiebreak
    etype[i] = r;
    atomicAdd(&cnt[r * NN + dst[i]], 1);
}

__global__ void k_inv(const int* __restrict__ cnt, float* __restrict__ inv) {
    int i = blockIdx.x * blockDim.x + threadIdx.x;
    if (i >= NREL * NN) return;
    int c = cnt[i];
    inv[i] = 1.0f / (float)(c > 1 ? c : 1);
}

// ---------------- bucket allocator: off[i] = fetch_add(total, cnt[i]) --------
__global__ void k_alloc(const int* __restrict__ cnt, int* __restrict__ off,
                        int* __restrict__ total) {
    int i = blockIdx.x * blockDim.x + threadIdx.x;
    if (i >= NREL * NN) return;
    off[i] = atomicAdd(total, cnt[i]);   // wave-coalesced by atomic optimizer
}

// ---------------- fill CSR: srcs[pos] = src[e], bucketed by (rel,dst) --------
__global__ void k_fill(const int* __restrict__ src, const int* __restrict__ dst,
                       const int* __restrict__ etype,
                       int* __restrict__ cursor, int* __restrict__ srcs, int E) {
    int i = blockIdx.x * blockDim.x + threadIdx.x;
    if (i >= E) return;
    int key = etype[i] * NN + dst[i];
    int pos = atomicAdd(&cursor[key], 1);
    srcs[pos] = src[i];
}

// ---------------- x -> bf16 ----------------
__global__ void k_cvt_x(const float* __restrict__ x,
                        __hip_bfloat16* __restrict__ xb, int n4) {
    int i = blockIdx.x * blockDim.x + threadIdx.x;
    if (i >= n4) return;
    float4 v = reinterpret_cast<const float4*>(x)[i];
    __hip_bfloat162 a = __float22bfloat162_rn(make_float2(v.x, v.y));
    __hip_bfloat162 b = __float22bfloat162_rn(make_float2(v.z, v.w));
    reinterpret_cast<__hip_bfloat162*>(xb)[i * 2 + 0] = a;
    reinterpret_cast<__hip_bfloat162*>(xb)[i * 2 + 1] = b;
}

// ---------------- weights: transpose + concat + bf16 ----------------
// wt[0:16384)                 : Wtp[n][k]   = Wf[k][n]              (K=128)
// wt[16384 + l*49152 + n*384+k]: layer l, k<128 -> root, 128..255 -> W0, else W1
__global__ void k_prep_w(const float* __restrict__ Wf,
                         const float* __restrict__ cw,
                         const float* __restrict__ cr,
                         __hip_bfloat16* __restrict__ wt) {
    int idx = blockIdx.x * blockDim.x + threadIdx.x;
    if (idx >= 16384 + 3 * 49152) return;
    float v;
    if (idx < 16384) {
        int n = idx >> 7, k = idx & 127;
        v = Wf[k * 128 + n];
    } else {
        int j = idx - 16384;
        int l = j / 49152; j %= 49152;
        int n = j / 384, k = j % 384;
        if (k < 128)      v = cr[((size_t)l * 128 + k) * 128 + n];
        else if (k < 256) v = cw[((size_t)(l * 2 + 0) * 128 + (k - 128)) * 128 + n];
        else              v = cw[((size_t)(l * 2 + 1) * 128 + (k - 256)) * 128 + n];
    }
    wt[idx] = __float2bfloat16(v);
}

// ---------------- aggregation: one wave per (rel,node), bf16 in/out ----------
__global__ __launch_bounds__(256)
void k_aggregate(const __hip_bfloat16* __restrict__ h,
                 const int* __restrict__ srcs,
                 const int* __restrict__ off, const int* __restrict__ cnt,
                 const float* __restrict__ inv,
                 __hip_bfloat16* __restrict__ agg) {
    int wid = (blockIdx.x * blockDim.x + threadIdx.x) >> 6;
    int lane = threadIdx.x & 63;
    if (wid >= NREL * NN) return;
    int start = off[wid], end = start + cnt[wid];
    float2 acc = make_float2(0.f, 0.f);
    int e = start;
    for (; e + 1 < end; e += 2) {       // 2 loads in flight
        int s0 = srcs[e], s1 = srcs[e + 1];
        float2 v0 = __bfloat1622float2(
            *reinterpret_cast<const __hip_bfloat162*>(h + (size_t)s0 * D + lane * 2));
        float2 v1 = __bfloat1622float2(
            *reinterpret_cast<const __hip_bfloat162*>(h + (size_t)s1 * D + lane * 2));
        acc.x += v0.x + v1.x;
        acc.y += v0.y + v1.y;
    }
    if (e < end) {
        float2 v0 = __bfloat1622float2(
            *reinterpret_cast<const __hip_bfloat162*>(h + (size_t)srcs[e] * D + lane * 2));
        acc.x += v0.x; acc.y += v0.y;
    }
    float sc = inv[wid];
    *reinterpret_cast<__hip_bfloat162*>(agg + (size_t)wid * D + lane * 2) =
        __float22bfloat162_rn(make_float2(acc.x * sc, acc.y * sc));
}

// ---------------- MFMA GEMM: out = relu([A0|A1|A2] @ Wt^T + bias) ------------
// BM=128 rows/block, 4 waves (wave w: rows w*32..w*32+31), full N=128.
// A fragments direct from global (each A row read exactly once per grid).
// B tile [128n][64k] bf16 staged in LDS with XOR swizzle (byte ^= (row&7)<<4).
template <int KTOT, bool OUT_F32>
__global__ __launch_bounds__(256)
void k_gemm_mfma(const __hip_bfloat16* __restrict__ A0,
                 const __hip_bfloat16* __restrict__ A1,
                 const __hip_bfloat16* __restrict__ A2,
                 const __hip_bfloat16* __restrict__ Wt,   // [128][KTOT]
                 const float* __restrict__ bias,
                 void* __restrict__ outv, int N) {
    __shared__ uint4 sB4[1024];            // 16 KB
    char* sB = (char*)sB4;
    const int tid = threadIdx.x;
    const int w = tid >> 6;
    const int l16 = tid & 15, lg = (tid & 63) >> 4;
    const __hip_bfloat16* As[3] = {A0, A1, A2};

    f32x4 acc[2][8];
#pragma unroll
    for (int m = 0; m < 2; m++)
#pragma unroll
        for (int n = 0; n < 8; n++) acc[m][n] = (f32x4)(0.f);

    const size_t row0 = (size_t)blockIdx.x * BM;
    const int NKB = KTOT / 64;
#pragma unroll
    for (int kb = 0; kb < NKB; ++kb) {
        const __hip_bfloat16* Ac = As[kb >> 1];
        const int koff = (kb & 1) * 64;
        // A fragments: lane l -> A[row0 + w*32 + mb*16 + l16][koff + kk*32 + lg*8 ..+8]
        bf16x8 afr[2][2];
#pragma unroll
        for (int mb = 0; mb < 2; ++mb)
#pragma unroll
            for (int kk = 0; kk < 2; ++kk) {
                int r = (int)row0 + w * 32 + mb * 16 + l16;
                if (r >= N) r = N - 1;              // clamped; store-guarded later
                afr[mb][kk] = *reinterpret_cast<const bf16x8*>(
                    Ac + (size_t)r * D + koff + kk * 32 + lg * 8);
            }
        __syncthreads();   // previous kb's sB reads complete
        // stage B tile: rows = n (128), cols = 64 bf16 of k
        {
            int trow = tid >> 3;
            int tb = (tid & 7) * 16;               // byte col within 128B row
#pragma unroll
            for (int p = 0; p < 4; ++p) {
                int rr = trow + p * 32;
                uint4 v = *reinterpret_cast<const uint4*>(
                    (const char*)(Wt + (size_t)rr * KTOT + kb * 64) + tb);
                *reinterpret_cast<uint4*>(sB + rr * 128 + (tb ^ ((rr & 7) << 4))) = v;
            }
        }
        __syncthreads();
#pragma unroll
        for (int kk = 0; kk < 2; ++kk) {
#pragma unroll
            for (int nb = 0; nb < 8; ++nb) {
                int brow = nb * 16 + l16;
                int bcol = kk * 64 + lg * 16;
                bf16x8 bfr = *reinterpret_cast<const bf16x8*>(
                    sB + brow * 128 + (bcol ^ ((brow & 7) << 4)));
                acc[0][nb] = __builtin_amdgcn_mfma_f32_16x16x32_bf16(
                    afr[0][kk], bfr, acc[0][nb], 0, 0, 0);
                acc[1][nb] = __builtin_amdgcn_mfma_f32_16x16x32_bf16(
                    afr[1][kk], bfr, acc[1][nb], 0, 0, 0);
            }
        }
    }
    // epilogue: D elem (row = w*32 + mb*16 + lg*4 + r, col = nb*16 + l16)
#pragma unroll
    for (int nb = 0; nb < 8; ++nb) {
        int n = nb * 16 + l16;
        float bv = bias[n];
#pragma unroll
        for (int mb = 0; mb < 2; ++mb) {
#pragma unroll
            for (int r = 0; r < 4; ++r) {
                long grow = (long)row0 + w * 32 + mb * 16 + lg * 4 + r;
                if (grow < N) {
                    float v = acc[mb][nb][r] + bv;
                    v = v > 0.f ? v : 0.f;
                    if (OUT_F32)
                        ((float*)outv)[(size_t)grow * D + n] = v;
                    else
                        ((__hip_bfloat16*)outv)[(size_t)grow * D + n] =
                            __float2bfloat16(v);
                }
            }
        }
    }
}

extern "C" void kernel_launch(void* const* d_in, const int* in_sizes, int n_in,
                              void* d_out, int out_size, void* d_ws, size_t ws_size,
                              hipStream_t stream) {
    const float* x    = (const float*)d_in[0];
    const int*   ei   = (const int*)d_in[1];
    const float* attr = (const float*)d_in[2];
    const float* Wf   = (const float*)d_in[3];
    const float* bf   = (const float*)d_in[4];
    const float* cw   = (const float*)d_in[5];  // [3][2][128][128]
    const float* cr   = (const float*)d_in[6];  // [3][128][128]
    const float* cb   = (const float*)d_in[7];  // [3][128]
    const int* src  = ei;
    const int* dstv = ei + NE;

    // workspace layout (bytes)
    char* p = (char*)d_ws;
    __hip_bfloat16* h0   = (__hip_bfloat16*)p; p += (size_t)NN * D * 2;
    __hip_bfloat16* h1   = (__hip_bfloat16*)p; p += (size_t)NN * D * 2;
    __hip_bfloat16* aggb = (__hip_bfloat16*)p; p += (size_t)2 * NN * D * 2;
    __hip_bfloat16* xb   = (__hip_bfloat16*)p; p += (size_t)NN * D * 2;
    __hip_bfloat16* wt   = (__hip_bfloat16*)p; p += (size_t)(16384 + 3 * 49152) * 2;
    float* inv  = (float*)p;                p += (size_t)2 * NN * 4;
    int*   cnt  = (int*)p;                  p += (size_t)2 * NN * 4;
    int*   etyp = (int*)p;                  p += (size_t)NE * 4;
    int*   off  = (int*)p;                  p += (size_t)2 * NN * 4;
    int*   cur  = (int*)p;                  p += (size_t)2 * NN * 4;
    int*   srcs = (int*)p;                  p += (size_t)NE * 4;
    int*   total= (int*)p;

    float* outp = (float*)d_out;

    // ---- layer-invariant preprocessing ----
    hipMemsetAsync(cnt, 0, (size_t)2 * NN * sizeof(int), stream);
    hipMemsetAsync(total, 0, sizeof(int), stream);
    k_etype_count<<<(NE + 255) / 256, 256, 0, stream>>>(attr, dstv, etyp, cnt, NE);
    k_inv<<<(2 * NN + 255) / 256, 256, 0, stream>>>(cnt, inv);
    k_alloc<<<(2 * NN + 255) / 256, 256, 0, stream>>>(cnt, off, total);
    hipMemcpyAsync(cur, off, (size_t)2 * NN * sizeof(int),
                   hipMemcpyDeviceToDevice, stream);
    k_fill<<<(NE + 255) / 256, 256, 0, stream>>>(src, dstv, etyp, cur, srcs, NE);
    k_cvt_x<<<(NN * D / 4 + 255) / 256, 256, 0, stream>>>(x, xb, NN * D / 4);
    k_prep_w<<<(16384 + 3 * 49152 + 255) / 256, 256, 0, stream>>>(Wf, cw, cr, wt);

    const int gblocks = (NN + BM - 1) / BM;
    // input projection: h0 = relu(xb @ Wtp^T + bf)
    k_gemm_mfma<128, false><<<gblocks, 256, 0, stream>>>(
        xb, xb, xb, wt, bf, h0, NN);

    const int ablocks = (2 * NN * 64 + 255) / 256;  // one wave per (rel,node)
    for (int l = 0; l < 3; ++l) {
        const __hip_bfloat16* hin = (l == 1) ? h1 : h0;
        k_aggregate<<<ablocks, 256, 0, stream>>>(hin, srcs, off, cnt, inv, aggb);
        const __hip_bfloat16* wl = wt + 16384 + (size_t)l * 49152;
        const float* bl = cb + (size_t)l * D;
        if (l == 2) {
            k_gemm_mfma<384, true><<<gblocks, 256, 0, stream>>>(
                hin, aggb, aggb + (size_t)NN * D, wl, bl, outp, NN);
        } else {
            __hip_bfloat16* hout = (l == 0) ? h1 : h0;
            k_gemm_mfma<384, false><<<gblocks, 256, 0, stream>>>(
                hin, aggb, aggb + (size_t)NN * D, wl, bl, hout, NN);
        }
    }
}

// Round 6
// 284.027 us; speedup vs baseline: 6.4762x; 1.1242x over previous
//
#include <hip/hip_runtime.h>
#include <hip/hip_bf16.h>

#define NN 50000
#define NE 600000
#define D 128
#define NREL 2
#define BM 128

typedef __attribute__((ext_vector_type(8))) short bf16x8;   // 8 bf16 (4 VGPRs)
typedef __attribute__((ext_vector_type(4))) float f32x4;    // 4 fp32 acc

__device__ __forceinline__ float bf2f(short s) {
    return __uint_as_float(((unsigned int)(unsigned short)s) << 16);
}

// ---------------- edge type + per-relation in-degree ----------------
__global__ void k_etype_count(const float* __restrict__ attr,
                              const int* __restrict__ dst,
                              int* __restrict__ etype,
                              int* __restrict__ cnt, int E) {
    int i = blockIdx.x * blockDim.x + threadIdx.x;
    if (i >= E) return;
    float2 a = reinterpret_cast<const float2*>(attr)[i];
    int r = (a.y > a.x) ? 1 : 0;   // argmax, first-index tiebreak
    etype[i] = r;
    atomicAdd(&cnt[r * NN + dst[i]], 1);
}

__global__ void k_inv(const int* __restrict__ cnt, float* __restrict__ inv) {
    int i = blockIdx.x * blockDim.x + threadIdx.x;
    if (i >= NREL * NN) return;
    int c = cnt[i];
    inv[i] = 1.0f / (float)(c > 1 ? c : 1);
}

// ---------------- bucket allocator: off[i] = fetch_add(total, cnt[i]) --------
__global__ void k_alloc(const int* __restrict__ cnt, int* __restrict__ off,
                        int* __restrict__ total) {
    int i = blockIdx.x * blockDim.x + threadIdx.x;
    if (i >= NREL * NN) return;
    off[i] = atomicAdd(total, cnt[i]);   // wave-coalesced by atomic optimizer
}

// ---------------- fill CSR: srcs[pos] = src[e], bucketed by (rel,dst) --------
__global__ void k_fill(const int* __restrict__ src, const int* __restrict__ dst,
                       const int* __restrict__ etype,
                       int* __restrict__ cursor, int* __restrict__ srcs, int E) {
    int i = blockIdx.x * blockDim.x + threadIdx.x;
    if (i >= E) return;
    int key = etype[i] * NN + dst[i];
    int pos = atomicAdd(&cursor[key], 1);
    srcs[pos] = src[i];
}

// ---------------- x -> bf16 ----------------
__global__ void k_cvt_x(const float* __restrict__ x,
                        __hip_bfloat16* __restrict__ xb, int n4) {
    int i = blockIdx.x * blockDim.x + threadIdx.x;
    if (i >= n4) return;
    float4 v = reinterpret_cast<const float4*>(x)[i];
    __hip_bfloat162 a = __float22bfloat162_rn(make_float2(v.x, v.y));
    __hip_bfloat162 b = __float22bfloat162_rn(make_float2(v.z, v.w));
    reinterpret_cast<__hip_bfloat162*>(xb)[i * 2 + 0] = a;
    reinterpret_cast<__hip_bfloat162*>(xb)[i * 2 + 1] = b;
}

// ---------------- weights: transpose + concat + bf16 ----------------
__global__ void k_prep_w(const float* __restrict__ Wf,
                         const float* __restrict__ cw,
                         const float* __restrict__ cr,
                         __hip_bfloat16* __restrict__ wt) {
    int idx = blockIdx.x * blockDim.x + threadIdx.x;
    if (idx >= 16384 + 3 * 49152) return;
    float v;
    if (idx < 16384) {
        int n = idx >> 7, k = idx & 127;
        v = Wf[k * 128 + n];
    } else {
        int j = idx - 16384;
        int l = j / 49152; j %= 49152;
        int n = j / 384, k = j % 384;
        if (k < 128)      v = cr[((size_t)l * 128 + k) * 128 + n];
        else if (k < 256) v = cw[((size_t)(l * 2 + 0) * 128 + (k - 128)) * 128 + n];
        else              v = cw[((size_t)(l * 2 + 1) * 128 + (k - 256)) * 128 + n];
    }
    wt[idx] = __float2bfloat16(v);
}

// ---------------- aggregation: one wave per (rel,node) bucket ----------------
// 4 x 16-lane groups; lane loads 16B (bf16x8); group g handles edges
// j = base+g and base+g+4 -> up to 8 gathers in flight/wave.
// CORRECTNESS: the loop bound is wave-uniform (c is per-bucket, shared by the
// whole wave), so every __shfl executes with all 64 lanes active (divergent
// __shfl reads exec-masked lanes -> undefined on CDNA). Only the plain
// gather-loads/accumulates are predicated.
__global__ __launch_bounds__(256)
void k_aggregate(const __hip_bfloat16* __restrict__ h,
                 const int* __restrict__ srcs,
                 const int* __restrict__ off, const int* __restrict__ cnt,
                 const float* __restrict__ inv,
                 __hip_bfloat16* __restrict__ agg) {
    int wid = (blockIdx.x * blockDim.x + threadIdx.x) >> 6;
    int lane = threadIdx.x & 63;
    if (wid >= NREL * NN) return;
    int start = off[wid], c = cnt[wid];
    int g = lane >> 4, l16 = lane & 15;

    int sv = (lane < c) ? srcs[start + lane] : 0;   // one coalesced index load

    float acc[8];
#pragma unroll
    for (int i = 0; i < 8; i++) acc[i] = 0.f;

    for (int base = 0; base < c; base += 8) {       // wave-uniform trip count
        int j0 = base + g, j1 = base + g + 4;
        int t0 = __shfl(sv, j0 & 63);               // full-exec shfl
        int t1 = __shfl(sv, j1 & 63);
        int s0 = (j0 < 64) ? t0 : ((j0 < c) ? srcs[start + j0] : 0);
        int s1 = (j1 < 64) ? t1 : ((j1 < c) ? srcs[start + j1] : 0);
        if (j0 < c) {
            bf16x8 v0 = *reinterpret_cast<const bf16x8*>(
                h + (size_t)s0 * D + l16 * 8);
#pragma unroll
            for (int i = 0; i < 8; i++) acc[i] += bf2f(v0[i]);
        }
        if (j1 < c) {
            bf16x8 v1 = *reinterpret_cast<const bf16x8*>(
                h + (size_t)s1 * D + l16 * 8);
#pragma unroll
            for (int i = 0; i < 8; i++) acc[i] += bf2f(v1[i]);
        }
    }

    // reduce across the 4 groups (lanes l16, l16+16, l16+32, l16+48)
#pragma unroll
    for (int i = 0; i < 8; i++) acc[i] += __shfl_xor(acc[i], 16);
#pragma unroll
    for (int i = 0; i < 8; i++) acc[i] += __shfl_xor(acc[i], 32);

    if (g == 0) {
        float sc = inv[wid];
        union { bf16x8 v; __hip_bfloat162 h2[4]; } o;
#pragma unroll
        for (int i = 0; i < 4; i++)
            o.h2[i] = __float22bfloat162_rn(
                make_float2(acc[2 * i] * sc, acc[2 * i + 1] * sc));
        *reinterpret_cast<bf16x8*>(agg + (size_t)wid * D + l16 * 8) = o.v;
    }
}

// ---------------- MFMA GEMM: out = relu([A0|A1|A2] @ Wt^T + bias) ------------
template <int KTOT, bool OUT_F32>
__global__ __launch_bounds__(256)
void k_gemm_mfma(const __hip_bfloat16* __restrict__ A0,
                 const __hip_bfloat16* __restrict__ A1,
                 const __hip_bfloat16* __restrict__ A2,
                 const __hip_bfloat16* __restrict__ Wt,   // [128][KTOT]
                 const float* __restrict__ bias,
                 void* __restrict__ outv, int N) {
    __shared__ uint4 sB4[1024];            // 16 KB
    char* sB = (char*)sB4;
    const int tid = threadIdx.x;
    const int w = tid >> 6;
    const int l16 = tid & 15, lg = (tid & 63) >> 4;
    const __hip_bfloat16* As[3] = {A0, A1, A2};

    f32x4 acc[2][8];
#pragma unroll
    for (int m = 0; m < 2; m++)
#pragma unroll
        for (int n = 0; n < 8; n++) acc[m][n] = (f32x4)(0.f);

    const size_t row0 = (size_t)blockIdx.x * BM;
    const int NKB = KTOT / 64;
#pragma unroll
    for (int kb = 0; kb < NKB; ++kb) {
        const __hip_bfloat16* Ac = As[kb >> 1];
        const int koff = (kb & 1) * 64;
        bf16x8 afr[2][2];
#pragma unroll
        for (int mb = 0; mb < 2; ++mb)
#pragma unroll
            for (int kk = 0; kk < 2; ++kk) {
                int r = (int)row0 + w * 32 + mb * 16 + l16;
                if (r >= N) r = N - 1;              // clamped; store-guarded later
                afr[mb][kk] = *reinterpret_cast<const bf16x8*>(
                    Ac + (size_t)r * D + koff + kk * 32 + lg * 8);
            }
        __syncthreads();   // previous kb's sB reads complete
        {
            int trow = tid >> 3;
            int tb = (tid & 7) * 16;               // byte col within 128B row
#pragma unroll
            for (int p = 0; p < 4; ++p) {
                int rr = trow + p * 32;
                uint4 v = *reinterpret_cast<const uint4*>(
                    (const char*)(Wt + (size_t)rr * KTOT + kb * 64) + tb);
                *reinterpret_cast<uint4*>(sB + rr * 128 + (tb ^ ((rr & 7) << 4))) = v;
            }
        }
        __syncthreads();
#pragma unroll
        for (int kk = 0; kk < 2; ++kk) {
#pragma unroll
            for (int nb = 0; nb < 8; ++nb) {
                int brow = nb * 16 + l16;
                int bcol = kk * 64 + lg * 16;
                bf16x8 bfr = *reinterpret_cast<const bf16x8*>(
                    sB + brow * 128 + (bcol ^ ((brow & 7) << 4)));
                acc[0][nb] = __builtin_amdgcn_mfma_f32_16x16x32_bf16(
                    afr[0][kk], bfr, acc[0][nb], 0, 0, 0);
                acc[1][nb] = __builtin_amdgcn_mfma_f32_16x16x32_bf16(
                    afr[1][kk], bfr, acc[1][nb], 0, 0, 0);
            }
        }
    }
#pragma unroll
    for (int nb = 0; nb < 8; ++nb) {
        int n = nb * 16 + l16;
        float bv = bias[n];
#pragma unroll
        for (int mb = 0; mb < 2; ++mb) {
#pragma unroll
            for (int r = 0; r < 4; ++r) {
                long grow = (long)row0 + w * 32 + mb * 16 + lg * 4 + r;
                if (grow < N) {
                    float v = acc[mb][nb][r] + bv;
                    v = v > 0.f ? v : 0.f;
                    if (OUT_F32)
                        ((float*)outv)[(size_t)grow * D + n] = v;
                    else
                        ((__hip_bfloat16*)outv)[(size_t)grow * D + n] =
                            __float2bfloat16(v);
                }
            }
        }
    }
}

extern "C" void kernel_launch(void* const* d_in, const int* in_sizes, int n_in,
                              void* d_out, int out_size, void* d_ws, size_t ws_size,
                              hipStream_t stream) {
    const float* x    = (const float*)d_in[0];
    const int*   ei   = (const int*)d_in[1];
    const float* attr = (const float*)d_in[2];
    const float* Wf   = (const float*)d_in[3];
    const float* bf   = (const float*)d_in[4];
    const float* cw   = (const float*)d_in[5];  // [3][2][128][128]
    const float* cr   = (const float*)d_in[6];  // [3][128][128]
    const float* cb   = (const float*)d_in[7];  // [3][128]
    const int* src  = ei;
    const int* dstv = ei + NE;

    // workspace layout (bytes)
    char* p = (char*)d_ws;
    __hip_bfloat16* h0   = (__hip_bfloat16*)p; p += (size_t)NN * D * 2;
    __hip_bfloat16* h1   = (__hip_bfloat16*)p; p += (size_t)NN * D * 2;
    __hip_bfloat16* aggb = (__hip_bfloat16*)p; p += (size_t)2 * NN * D * 2;
    __hip_bfloat16* xb   = (__hip_bfloat16*)p; p += (size_t)NN * D * 2;
    __hip_bfloat16* wt   = (__hip_bfloat16*)p; p += (size_t)(16384 + 3 * 49152) * 2;
    float* inv  = (float*)p;                p += (size_t)2 * NN * 4;
    int*   cnt  = (int*)p;                  p += (size_t)2 * NN * 4;
    int*   etyp = (int*)p;                  p += (size_t)NE * 4;
    int*   off  = (int*)p;                  p += (size_t)2 * NN * 4;
    int*   cur  = (int*)p;                  p += (size_t)2 * NN * 4;
    int*   srcs = (int*)p;                  p += (size_t)NE * 4;
    int*   total= (int*)p;

    float* outp = (float*)d_out;

    // ---- layer-invariant preprocessing ----
    hipMemsetAsync(cnt, 0, (size_t)2 * NN * sizeof(int), stream);
    hipMemsetAsync(total, 0, sizeof(int), stream);
    k_etype_count<<<(NE + 255) / 256, 256, 0, stream>>>(attr, dstv, etyp, cnt, NE);
    k_inv<<<(2 * NN + 255) / 256, 256, 0, stream>>>(cnt, inv);
    k_alloc<<<(2 * NN + 255) / 256, 256, 0, stream>>>(cnt, off, total);
    hipMemcpyAsync(cur, off, (size_t)2 * NN * sizeof(int),
                   hipMemcpyDeviceToDevice, stream);
    k_fill<<<(NE + 255) / 256, 256, 0, stream>>>(src, dstv, etyp, cur, srcs, NE);
    k_cvt_x<<<(NN * D / 4 + 255) / 256, 256, 0, stream>>>(x, xb, NN * D / 4);
    k_prep_w<<<(16384 + 3 * 49152 + 255) / 256, 256, 0, stream>>>(Wf, cw, cr, wt);

    const int gblocks = (NN + BM - 1) / BM;
    // input projection: h0 = relu(xb @ Wtp^T + bf)
    k_gemm_mfma<128, false><<<gblocks, 256, 0, stream>>>(
        xb, xb, xb, wt, bf, h0, NN);

    const int ablocks = (2 * NN * 64 + 255) / 256;  // one wave per (rel,node)
    for (int l = 0; l < 3; ++l) {
        const __hip_bfloat16* hin = (l == 1) ? h1 : h0;
        k_aggregate<<<ablocks, 256, 0, stream>>>(hin, srcs, off, cnt, inv, aggb);
        const __hip_bfloat16* wl = wt + 16384 + (size_t)l * 49152;
        const float* bl = cb + (size_t)l * D;
        if (l == 2) {
            k_gemm_mfma<384, true><<<gblocks, 256, 0, stream>>>(
                hin, aggb, aggb + (size_t)NN * D, wl, bl, outp, NN);
        } else {
            __hip_bfloat16* hout = (l == 0) ? h1 : h0;
            k_gemm_mfma<384, false><<<gblocks, 256, 0, stream>>>(
                hin, aggb, aggb + (size_t)NN * D, wl, bl, hout, NN);
        }
    }
}